// Round 1
// baseline (180.167 us; speedup 1.0000x reference)
//
#include <hip/hip_runtime.h>
#include <math.h>

#define NPATHS   1024
#define CANVAS_H 224
#define CANVAS_W 224
#define NSEG     4
#define NSAMP    49          // linspace(0,1,50)[:-1] -> t_i = i/49, i=0..48
#define SOFT_INV 50.0f       // 1/0.02

// Per-path packed record in workspace: cx, cy, r, alpha, cr, cg, cb, pad
#define PD_STRIDE 8

__global__ __launch_bounds__(256) void path_setup_kernel(
    const float* __restrict__ cps,     // (P, 4, 4, 2)
    const float* __restrict__ colors,  // (P, 4)
    float* __restrict__ pd)            // (P, 8)
{
    int p = blockIdx.x * blockDim.x + threadIdx.x;
    if (p >= NPATHS) return;

    const float* cp = cps + (size_t)p * NSEG * 4 * 2;
    float x[NSEG][4], y[NSEG][4];
#pragma unroll
    for (int s = 0; s < NSEG; ++s)
#pragma unroll
        for (int c = 0; c < 4; ++c) {
            x[s][c] = cp[(s * 4 + c) * 2 + 0];
            y[s][c] = cp[(s * 4 + c) * 2 + 1];
        }

    // Pass 1: mean of all 196 sampled points
    float sx = 0.0f, sy = 0.0f;
    for (int i = 0; i < NSAMP; ++i) {
        float t  = (float)i * (1.0f / 49.0f);
        float mt = 1.0f - t;
        float b0 = mt * mt * mt;
        float b1 = 3.0f * mt * mt * t;
        float b2 = 3.0f * mt * t * t;
        float b3 = t * t * t;
#pragma unroll
        for (int s = 0; s < NSEG; ++s) {
            sx += b0 * x[s][0] + b1 * x[s][1] + b2 * x[s][2] + b3 * x[s][3];
            sy += b0 * y[s][0] + b1 * y[s][1] + b2 * y[s][2] + b3 * y[s][3];
        }
    }
    const float inv_n = 1.0f / (float)(NSEG * NSAMP);
    float cx = sx * inv_n;
    float cy = sy * inv_n;

    // Pass 2: mean distance to center (recompute points — cheap)
    float sr = 0.0f;
    for (int i = 0; i < NSAMP; ++i) {
        float t  = (float)i * (1.0f / 49.0f);
        float mt = 1.0f - t;
        float b0 = mt * mt * mt;
        float b1 = 3.0f * mt * mt * t;
        float b2 = 3.0f * mt * t * t;
        float b3 = t * t * t;
#pragma unroll
        for (int s = 0; s < NSEG; ++s) {
            float px = b0 * x[s][0] + b1 * x[s][1] + b2 * x[s][2] + b3 * x[s][3];
            float py = b0 * y[s][0] + b1 * y[s][1] + b2 * y[s][2] + b3 * y[s][3];
            float dx = px - cx;
            float dy = py - cy;
            sr += sqrtf(dx * dx + dy * dy);
        }
    }
    float r = sr * inv_n;

    const float* col = colors + (size_t)p * 4;
    float* o = pd + (size_t)p * PD_STRIDE;
    o[0] = cx;
    o[1] = cy;
    o[2] = r;
    o[3] = col[3];   // alpha
    o[4] = col[0];   // r
    o[5] = col[1];   // g
    o[6] = col[2];   // b
    o[7] = 0.0f;
}

__global__ __launch_bounds__(128) void composite_kernel(
    const float* __restrict__ pd,   // (P, 8)
    float* __restrict__ out)        // (3, H, W)
{
    __shared__ float lds[NPATHS * PD_STRIDE];  // 32 KB

    // Cooperative stage: 8192 floats = 2048 float4 / 128 threads = 16 each
    const float4* src4 = reinterpret_cast<const float4*>(pd);
    float4* dst4 = reinterpret_cast<float4*>(lds);
    for (int i = threadIdx.x; i < NPATHS * PD_STRIDE / 4; i += blockDim.x)
        dst4[i] = src4[i];
    __syncthreads();

    int pix = blockIdx.x * blockDim.x + threadIdx.x;   // 50176 = 392*128 exact
    int yy = pix / CANVAS_W;
    int xx = pix - yy * CANVAS_W;
    float px = (float)xx * (1.0f / 223.0f);   // grid_x varies over cols
    float py = (float)yy * (1.0f / 223.0f);   // grid_y varies over rows

    float R = 1.0f, G = 1.0f, B = 1.0f;

    for (int p = 0; p < NPATHS; ++p) {
        float4 d0 = *reinterpret_cast<const float4*>(&lds[p * PD_STRIDE]);
        float4 d1 = *reinterpret_cast<const float4*>(&lds[p * PD_STRIDE + 4]);
        float dx = px - d0.x;
        float dy = py - d0.y;
        float dist = sqrtf(dx * dx + dy * dy);
        float xarg = (d0.z - dist) * SOFT_INV;
        // m = alpha * sigmoid(xarg); saturates to 0 correctly when exp -> inf
        float m = d0.w / (1.0f + __expf(-xarg));
        float om = 1.0f - m;
        R = R * om + d1.x * m;
        G = G * om + d1.y * m;
        B = B * om + d1.z * m;
    }

    out[0 * CANVAS_H * CANVAS_W + pix] = R;
    out[1 * CANVAS_H * CANVAS_W + pix] = G;
    out[2 * CANVAS_H * CANVAS_W + pix] = B;
}

extern "C" void kernel_launch(void* const* d_in, const int* in_sizes, int n_in,
                              void* d_out, int out_size, void* d_ws, size_t ws_size,
                              hipStream_t stream) {
    const float* cps    = (const float*)d_in[0];   // (1024, 4, 4, 2) fp32
    const float* colors = (const float*)d_in[1];   // (1024, 4) fp32
    float* out = (float*)d_out;                    // (3, 224, 224) fp32
    float* pd  = (float*)d_ws;                     // 1024 * 8 floats = 32 KB

    path_setup_kernel<<<(NPATHS + 255) / 256, 256, 0, stream>>>(cps, colors, pd);

    const int npix = CANVAS_H * CANVAS_W;          // 50176
    composite_kernel<<<npix / 128, 128, 0, stream>>>(pd, out);
}

// Round 2
// 69.314 us; speedup vs baseline: 2.5993x; 2.5993x over previous
//
#include <hip/hip_runtime.h>
#include <math.h>

#define NPATHS   1024
#define CANVAS_H 224
#define CANVAS_W 224
#define NPIX     (CANVAS_H * CANVAS_W)   // 50176
#define NSEG     4
#define NSAMP    49          // linspace(0,1,50)[:-1] -> t_i = i/49, i=0..48
#define SOFT_INV 50.0f       // 1/0.02
#define CULL_MARGIN 0.3f     // sigmoid(-15) ~ 3e-7; 1024 paths -> <= 3e-4 error

// Per-path record: [cx, cy, r, alpha, cr, cg, cb, rr_cull]
#define PD_STRIDE 8
#define PD_BYTES  (NPATHS * PD_STRIDE * 4)

__global__ __launch_bounds__(256) void path_setup_kernel(
    const float* __restrict__ cps,     // (P, 4, 4, 2)
    const float* __restrict__ colors,  // (P, 4)
    float* __restrict__ pd)            // (P, 8)
{
    int p = blockIdx.x * blockDim.x + threadIdx.x;
    if (p >= NPATHS) return;

    const float* cp = cps + (size_t)p * NSEG * 4 * 2;
    float x[NSEG][4], y[NSEG][4];
#pragma unroll
    for (int s = 0; s < NSEG; ++s)
#pragma unroll
        for (int c = 0; c < 4; ++c) {
            x[s][c] = cp[(s * 4 + c) * 2 + 0];
            y[s][c] = cp[(s * 4 + c) * 2 + 1];
        }

    float sx = 0.0f, sy = 0.0f;
    for (int i = 0; i < NSAMP; ++i) {
        float t  = (float)i * (1.0f / 49.0f);
        float mt = 1.0f - t;
        float b0 = mt * mt * mt;
        float b1 = 3.0f * mt * mt * t;
        float b2 = 3.0f * mt * t * t;
        float b3 = t * t * t;
#pragma unroll
        for (int s = 0; s < NSEG; ++s) {
            sx += b0 * x[s][0] + b1 * x[s][1] + b2 * x[s][2] + b3 * x[s][3];
            sy += b0 * y[s][0] + b1 * y[s][1] + b2 * y[s][2] + b3 * y[s][3];
        }
    }
    const float inv_n = 1.0f / (float)(NSEG * NSAMP);
    float cx = sx * inv_n;
    float cy = sy * inv_n;

    float sr = 0.0f;
    for (int i = 0; i < NSAMP; ++i) {
        float t  = (float)i * (1.0f / 49.0f);
        float mt = 1.0f - t;
        float b0 = mt * mt * mt;
        float b1 = 3.0f * mt * mt * t;
        float b2 = 3.0f * mt * t * t;
        float b3 = t * t * t;
#pragma unroll
        for (int s = 0; s < NSEG; ++s) {
            float px = b0 * x[s][0] + b1 * x[s][1] + b2 * x[s][2] + b3 * x[s][3];
            float py = b0 * y[s][0] + b1 * y[s][1] + b2 * y[s][2] + b3 * y[s][3];
            float dx = px - cx;
            float dy = py - cy;
            sr += sqrtf(dx * dx + dy * dy);
        }
    }
    float r = sr * inv_n;
    float rc = r + CULL_MARGIN;

    const float* col = colors + (size_t)p * 4;
    float* o = pd + (size_t)p * PD_STRIDE;
    o[0] = cx;
    o[1] = cy;
    o[2] = r;
    o[3] = col[3];   // alpha
    o[4] = col[0];
    o[5] = col[1];
    o[6] = col[2];
    o[7] = rc * rc;  // squared cull radius
}

// One block = one 16x8 pixel tile, for one chunk of CHUNK paths.
// Emits affine map (T, Ar, Ag, Ab) per pixel.
template<int CHUNK>
__global__ __launch_bounds__(128) void chunk_kernel(
    const float* __restrict__ pd,
    float4* __restrict__ cb)           // (K, NPIX) float4
{
    __shared__ float lds[CHUNK * PD_STRIDE];

    const int chunk = blockIdx.y;
    const float* src = pd + (size_t)chunk * CHUNK * PD_STRIDE;
    const float4* src4 = reinterpret_cast<const float4*>(src);
    float4* dst4 = reinterpret_cast<float4*>(lds);
    for (int i = threadIdx.x; i < CHUNK * PD_STRIDE / 4; i += 128)
        dst4[i] = src4[i];
    __syncthreads();

    // 14 tiles of 16 in x, 28 tiles of 8 in y -> 392 blocks in x
    const int tile   = blockIdx.x;
    const int tile_y = tile / 14;
    const int tile_x = tile - tile_y * 14;
    const int lx = threadIdx.x & 15;
    const int ly = threadIdx.x >> 4;
    const int xx = tile_x * 16 + lx;
    const int yy = tile_y * 8 + ly;
    const float px = (float)xx * (1.0f / 223.0f);
    const float py = (float)yy * (1.0f / 223.0f);

    float T = 1.0f, Ar = 0.0f, Ag = 0.0f, Ab = 0.0f;

    for (int p = 0; p < CHUNK; ++p) {
        float4 d0 = *reinterpret_cast<const float4*>(&lds[p * PD_STRIDE]);     // cx,cy,r,alpha
        float4 d1 = *reinterpret_cast<const float4*>(&lds[p * PD_STRIDE + 4]); // cr,cg,cb,rr
        float dx = px - d0.x;
        float dy = py - d0.y;
        float d2 = dx * dx + dy * dy;
        if (__any(d2 < d1.w)) {
            float dist = __builtin_amdgcn_sqrtf(d2);
            float xarg = (d0.z - dist) * SOFT_INV;
            float e = __expf(-xarg);
            float m = d0.w * __builtin_amdgcn_rcpf(1.0f + e);
            float om = 1.0f - m;
            T  = T * om;
            Ar = Ar * om + d1.x * m;
            Ag = Ag * om + d1.y * m;
            Ab = Ab * om + d1.z * m;
        }
    }

    const int pix = yy * CANVAS_W + xx;
    cb[(size_t)chunk * NPIX + pix] = make_float4(T, Ar, Ag, Ab);
}

__global__ __launch_bounds__(256) void combine_kernel(
    const float4* __restrict__ cb,     // (K, NPIX)
    float* __restrict__ out,           // (3, H, W)
    int K)
{
    int pix = blockIdx.x * 256 + threadIdx.x;   // 50176 = 196*256 exact
    float R = 1.0f, G = 1.0f, B = 1.0f;
    for (int k = 0; k < K; ++k) {
        float4 w = cb[(size_t)k * NPIX + pix];
        R = R * w.x + w.y;
        G = G * w.x + w.z;
        B = B * w.x + w.w;
    }
    out[pix]            = R;
    out[NPIX + pix]     = G;
    out[2 * NPIX + pix] = B;
}

// Fallback: direct sequential composite (if ws too small for chunk buffers)
__global__ __launch_bounds__(128) void composite_fallback_kernel(
    const float* __restrict__ pd,
    float* __restrict__ out)
{
    __shared__ float lds[NPATHS * PD_STRIDE];
    const float4* src4 = reinterpret_cast<const float4*>(pd);
    float4* dst4 = reinterpret_cast<float4*>(lds);
    for (int i = threadIdx.x; i < NPATHS * PD_STRIDE / 4; i += 128)
        dst4[i] = src4[i];
    __syncthreads();

    const int tile   = blockIdx.x;
    const int tile_y = tile / 14;
    const int tile_x = tile - tile_y * 14;
    const int lx = threadIdx.x & 15;
    const int ly = threadIdx.x >> 4;
    const int xx = tile_x * 16 + lx;
    const int yy = tile_y * 8 + ly;
    const float px = (float)xx * (1.0f / 223.0f);
    const float py = (float)yy * (1.0f / 223.0f);

    float R = 1.0f, G = 1.0f, B = 1.0f;
    for (int p = 0; p < NPATHS; ++p) {
        float4 d0 = *reinterpret_cast<const float4*>(&lds[p * PD_STRIDE]);
        float4 d1 = *reinterpret_cast<const float4*>(&lds[p * PD_STRIDE + 4]);
        float dx = px - d0.x;
        float dy = py - d0.y;
        float d2 = dx * dx + dy * dy;
        if (__any(d2 < d1.w)) {
            float dist = __builtin_amdgcn_sqrtf(d2);
            float xarg = (d0.z - dist) * SOFT_INV;
            float e = __expf(-xarg);
            float m = d0.w * __builtin_amdgcn_rcpf(1.0f + e);
            float om = 1.0f - m;
            R = R * om + d1.x * m;
            G = G * om + d1.y * m;
            B = B * om + d1.z * m;
        }
    }
    const int pix = yy * CANVAS_W + xx;
    out[pix]            = R;
    out[NPIX + pix]     = G;
    out[2 * NPIX + pix] = B;
}

extern "C" void kernel_launch(void* const* d_in, const int* in_sizes, int n_in,
                              void* d_out, int out_size, void* d_ws, size_t ws_size,
                              hipStream_t stream) {
    const float* cps    = (const float*)d_in[0];
    const float* colors = (const float*)d_in[1];
    float* out = (float*)d_out;
    float* pd  = (float*)d_ws;

    path_setup_kernel<<<(NPATHS + 255) / 256, 256, 0, stream>>>(cps, colors, pd);

    // Pick largest K in {8,4,2} whose chunk buffers fit in remaining ws
    size_t avail = ws_size > PD_BYTES ? ws_size - (size_t)PD_BYTES : 0;
    int K = 0;
    if      (avail >= (size_t)8 * NPIX * 16) K = 8;
    else if (avail >= (size_t)4 * NPIX * 16) K = 4;
    else if (avail >= (size_t)2 * NPIX * 16) K = 2;

    if (K == 0) {
        composite_fallback_kernel<<<392, 128, 0, stream>>>(pd, out);
        return;
    }

    float4* cb = reinterpret_cast<float4*>((char*)d_ws + PD_BYTES);
    dim3 grid(392, K);
    switch (K) {
        case 8: chunk_kernel<128><<<grid, 128, 0, stream>>>(pd, cb); break;
        case 4: chunk_kernel<256><<<grid, 128, 0, stream>>>(pd, cb); break;
        case 2: chunk_kernel<512><<<grid, 128, 0, stream>>>(pd, cb); break;
    }
    combine_kernel<<<NPIX / 256, 256, 0, stream>>>(cb, out, K);
}

// Round 3
// 64.352 us; speedup vs baseline: 2.7997x; 1.0771x over previous
//
#include <hip/hip_runtime.h>
#include <math.h>

#define NPATHS   1024
#define CANVAS_H 224
#define CANVAS_W 224
#define NPIX     (CANVAS_H * CANVAS_W)   // 50176
#define NSEG     4
#define NSAMP    49          // linspace(0,1,50)[:-1] -> t_i = i/49
#define K2EXP    72.134752f  // 50 / ln(2): sigmoid(50*(r-d)) = 1/(1+exp2((d-r)*K2EXP))
#define CULL_MARGIN 0.3f     // sigmoid(-15) ~ 3e-7; worst-case total err <= 3e-4

// Per-path record: [cx, cy, c2=-K2EXP*r, alpha, cr, cg, cb, rr_cull]
#define PD_STRIDE 8
#define PD_BYTES  (NPATHS * PD_STRIDE * 4)

__global__ __launch_bounds__(256) void path_setup_kernel(
    const float* __restrict__ cps,     // (P, 4, 4, 2)
    const float* __restrict__ colors,  // (P, 4)
    float* __restrict__ pd)            // (P, 8)
{
    int p = blockIdx.x * blockDim.x + threadIdx.x;
    if (p >= NPATHS) return;

    const float* cp = cps + (size_t)p * NSEG * 4 * 2;
    float x[NSEG][4], y[NSEG][4];
#pragma unroll
    for (int s = 0; s < NSEG; ++s)
#pragma unroll
        for (int c = 0; c < 4; ++c) {
            x[s][c] = cp[(s * 4 + c) * 2 + 0];
            y[s][c] = cp[(s * 4 + c) * 2 + 1];
        }

    float sx = 0.0f, sy = 0.0f;
    for (int i = 0; i < NSAMP; ++i) {
        float t  = (float)i * (1.0f / 49.0f);
        float mt = 1.0f - t;
        float b0 = mt * mt * mt;
        float b1 = 3.0f * mt * mt * t;
        float b2 = 3.0f * mt * t * t;
        float b3 = t * t * t;
#pragma unroll
        for (int s = 0; s < NSEG; ++s) {
            sx += b0 * x[s][0] + b1 * x[s][1] + b2 * x[s][2] + b3 * x[s][3];
            sy += b0 * y[s][0] + b1 * y[s][1] + b2 * y[s][2] + b3 * y[s][3];
        }
    }
    const float inv_n = 1.0f / (float)(NSEG * NSAMP);
    float cx = sx * inv_n;
    float cy = sy * inv_n;

    float sr = 0.0f;
    for (int i = 0; i < NSAMP; ++i) {
        float t  = (float)i * (1.0f / 49.0f);
        float mt = 1.0f - t;
        float b0 = mt * mt * mt;
        float b1 = 3.0f * mt * mt * t;
        float b2 = 3.0f * mt * t * t;
        float b3 = t * t * t;
#pragma unroll
        for (int s = 0; s < NSEG; ++s) {
            float px = b0 * x[s][0] + b1 * x[s][1] + b2 * x[s][2] + b3 * x[s][3];
            float py = b0 * y[s][0] + b1 * y[s][1] + b2 * y[s][2] + b3 * y[s][3];
            float dx = px - cx;
            float dy = py - cy;
            sr += sqrtf(dx * dx + dy * dy);
        }
    }
    float r = sr * inv_n;
    float rc = r + CULL_MARGIN;

    const float* col = colors + (size_t)p * 4;
    float* o = pd + (size_t)p * PD_STRIDE;
    o[0] = cx;
    o[1] = cy;
    o[2] = -K2EXP * r;   // c2
    o[3] = col[3];       // alpha
    o[4] = col[0];
    o[5] = col[1];
    o[6] = col[2];
    o[7] = rc * rc;      // squared cull radius
}

// One block = one 16x8 pixel tile for one chunk of CHUNK paths.
// Path records read with a uniform index -> scalar loads (sL1-cached), no LDS.
template<int CHUNK>
__global__ __launch_bounds__(128) void chunk_kernel(
    const float* __restrict__ pd,
    float4* __restrict__ cb)           // (K, NPIX) float4
{
    const int chunk = blockIdx.y;
    const float* src = pd + (size_t)chunk * CHUNK * PD_STRIDE;

    // 14 tiles of 16 in x, 28 tiles of 8 in y
    const int tile   = blockIdx.x;
    const int tile_y = tile / 14;
    const int tile_x = tile - tile_y * 14;
    const int lx = threadIdx.x & 15;
    const int ly = threadIdx.x >> 4;
    const int xx = tile_x * 16 + lx;
    const int yy = tile_y * 8 + ly;
    const float px = (float)xx * (1.0f / 223.0f);
    const float py = (float)yy * (1.0f / 223.0f);

    float T = 1.0f, Ar = 0.0f, Ag = 0.0f, Ab = 0.0f;

#pragma unroll 2
    for (int p = 0; p < CHUNK; ++p) {
        float4 d0 = *reinterpret_cast<const float4*>(src + p * PD_STRIDE);     // cx,cy,c2,alpha
        float4 d1 = *reinterpret_cast<const float4*>(src + p * PD_STRIDE + 4); // cr,cg,cb,rr
        float dx = px - d0.x;
        float dy = py - d0.y;
        float d2 = __builtin_fmaf(dx, dx, dy * dy);
        if (__any(d2 < d1.w)) {
            float dist = __builtin_amdgcn_sqrtf(d2);
            float e = __builtin_amdgcn_exp2f(__builtin_fmaf(dist, K2EXP, d0.z));
            float m = d0.w * __builtin_amdgcn_rcpf(1.0f + e);
            float om = 1.0f - m;
            T  = T * om;
            Ar = __builtin_fmaf(Ar, om, d1.x * m);
            Ag = __builtin_fmaf(Ag, om, d1.y * m);
            Ab = __builtin_fmaf(Ab, om, d1.z * m);
        }
    }

    const int pix = yy * CANVAS_W + xx;
    cb[(size_t)chunk * NPIX + pix] = make_float4(T, Ar, Ag, Ab);
}

__global__ __launch_bounds__(256) void combine_kernel(
    const float4* __restrict__ cb,     // (K, NPIX)
    float* __restrict__ out,           // (3, H, W)
    int K)
{
    int pix = blockIdx.x * 256 + threadIdx.x;   // 50176 = 196*256 exact
    float R = 1.0f, G = 1.0f, B = 1.0f;
    for (int k = 0; k < K; ++k) {
        float4 w = cb[(size_t)k * NPIX + pix];
        R = __builtin_fmaf(R, w.x, w.y);
        G = __builtin_fmaf(G, w.x, w.z);
        B = __builtin_fmaf(B, w.x, w.w);
    }
    out[pix]            = R;
    out[NPIX + pix]     = G;
    out[2 * NPIX + pix] = B;
}

// Fallback: direct sequential composite (ws too small for chunk buffers)
__global__ __launch_bounds__(128) void composite_fallback_kernel(
    const float* __restrict__ pd,
    float* __restrict__ out)
{
    const int tile   = blockIdx.x;
    const int tile_y = tile / 14;
    const int tile_x = tile - tile_y * 14;
    const int lx = threadIdx.x & 15;
    const int ly = threadIdx.x >> 4;
    const int xx = tile_x * 16 + lx;
    const int yy = tile_y * 8 + ly;
    const float px = (float)xx * (1.0f / 223.0f);
    const float py = (float)yy * (1.0f / 223.0f);

    float R = 1.0f, G = 1.0f, B = 1.0f;
#pragma unroll 2
    for (int p = 0; p < NPATHS; ++p) {
        float4 d0 = *reinterpret_cast<const float4*>(pd + p * PD_STRIDE);
        float4 d1 = *reinterpret_cast<const float4*>(pd + p * PD_STRIDE + 4);
        float dx = px - d0.x;
        float dy = py - d0.y;
        float d2 = __builtin_fmaf(dx, dx, dy * dy);
        if (__any(d2 < d1.w)) {
            float dist = __builtin_amdgcn_sqrtf(d2);
            float e = __builtin_amdgcn_exp2f(__builtin_fmaf(dist, K2EXP, d0.z));
            float m = d0.w * __builtin_amdgcn_rcpf(1.0f + e);
            float om = 1.0f - m;
            R = __builtin_fmaf(R, om, d1.x * m);
            G = __builtin_fmaf(G, om, d1.y * m);
            B = __builtin_fmaf(B, om, d1.z * m);
        }
    }
    const int pix = yy * CANVAS_W + xx;
    out[pix]            = R;
    out[NPIX + pix]     = G;
    out[2 * NPIX + pix] = B;
}

extern "C" void kernel_launch(void* const* d_in, const int* in_sizes, int n_in,
                              void* d_out, int out_size, void* d_ws, size_t ws_size,
                              hipStream_t stream) {
    const float* cps    = (const float*)d_in[0];
    const float* colors = (const float*)d_in[1];
    float* out = (float*)d_out;
    float* pd  = (float*)d_ws;

    path_setup_kernel<<<(NPATHS + 255) / 256, 256, 0, stream>>>(cps, colors, pd);

    size_t avail = ws_size > PD_BYTES ? ws_size - (size_t)PD_BYTES : 0;
    int K = 0;
    if      (avail >= (size_t)32 * NPIX * 16) K = 32;
    else if (avail >= (size_t)16 * NPIX * 16) K = 16;
    else if (avail >= (size_t)8  * NPIX * 16) K = 8;
    else if (avail >= (size_t)4  * NPIX * 16) K = 4;
    else if (avail >= (size_t)2  * NPIX * 16) K = 2;

    if (K == 0) {
        composite_fallback_kernel<<<392, 128, 0, stream>>>(pd, out);
        return;
    }

    float4* cb = reinterpret_cast<float4*>((char*)d_ws + PD_BYTES);
    dim3 grid(392, K);
    switch (K) {
        case 32: chunk_kernel<32> <<<grid, 128, 0, stream>>>(pd, cb); break;
        case 16: chunk_kernel<64> <<<grid, 128, 0, stream>>>(pd, cb); break;
        case 8:  chunk_kernel<128><<<grid, 128, 0, stream>>>(pd, cb); break;
        case 4:  chunk_kernel<256><<<grid, 128, 0, stream>>>(pd, cb); break;
        case 2:  chunk_kernel<512><<<grid, 128, 0, stream>>>(pd, cb); break;
    }
    combine_kernel<<<NPIX / 256, 256, 0, stream>>>(cb, out, K);
}

// Round 4
// 58.190 us; speedup vs baseline: 3.0962x; 1.1059x over previous
//
#include <hip/hip_runtime.h>
#include <math.h>

#define NPATHS   1024
#define CANVAS_H 224
#define CANVAS_W 224
#define NPIX     (CANVAS_H * CANVAS_W)   // 50176
#define NSEG     4
#define NSAMP    49          // linspace(0,1,50)[:-1] -> t_i = i/49
#define K2EXP    72.134752f  // 50/ln(2): sigmoid(50*(r-d)) = 1/(1+exp2((d-r)*K2EXP))
#define CULL_MARGIN 0.3f     // sigmoid(-15) ~ 3e-7; worst-case total err <= 3e-4

#define NWAVES   8
#define PPW      (NPATHS / NWAVES)       // 128 paths per wave

// Per-path record: [cx, cy, c2=-K2EXP*r, alpha, cr, cg, cb, rr_cull]
#define PD_STRIDE 8
#define PD_BYTES  (NPATHS * PD_STRIDE * 4)

__global__ __launch_bounds__(256) void path_setup_kernel(
    const float* __restrict__ cps,     // (P, 4, 4, 2)
    const float* __restrict__ colors,  // (P, 4)
    float* __restrict__ pd)            // (P, 8)
{
    int p = blockIdx.x * blockDim.x + threadIdx.x;
    if (p >= NPATHS) return;

    const float* cp = cps + (size_t)p * NSEG * 4 * 2;
    float x[NSEG][4], y[NSEG][4];
#pragma unroll
    for (int s = 0; s < NSEG; ++s)
#pragma unroll
        for (int c = 0; c < 4; ++c) {
            x[s][c] = cp[(s * 4 + c) * 2 + 0];
            y[s][c] = cp[(s * 4 + c) * 2 + 1];
        }

    float sx = 0.0f, sy = 0.0f;
    for (int i = 0; i < NSAMP; ++i) {
        float t  = (float)i * (1.0f / 49.0f);
        float mt = 1.0f - t;
        float b0 = mt * mt * mt;
        float b1 = 3.0f * mt * mt * t;
        float b2 = 3.0f * mt * t * t;
        float b3 = t * t * t;
#pragma unroll
        for (int s = 0; s < NSEG; ++s) {
            sx += b0 * x[s][0] + b1 * x[s][1] + b2 * x[s][2] + b3 * x[s][3];
            sy += b0 * y[s][0] + b1 * y[s][1] + b2 * y[s][2] + b3 * y[s][3];
        }
    }
    const float inv_n = 1.0f / (float)(NSEG * NSAMP);
    float cx = sx * inv_n;
    float cy = sy * inv_n;

    float sr = 0.0f;
    for (int i = 0; i < NSAMP; ++i) {
        float t  = (float)i * (1.0f / 49.0f);
        float mt = 1.0f - t;
        float b0 = mt * mt * mt;
        float b1 = 3.0f * mt * mt * t;
        float b2 = 3.0f * mt * t * t;
        float b3 = t * t * t;
#pragma unroll
        for (int s = 0; s < NSEG; ++s) {
            float px = b0 * x[s][0] + b1 * x[s][1] + b2 * x[s][2] + b3 * x[s][3];
            float py = b0 * y[s][0] + b1 * y[s][1] + b2 * y[s][2] + b3 * y[s][3];
            float dx = px - cx;
            float dy = py - cy;
            sr += sqrtf(dx * dx + dy * dy);
        }
    }
    float r = sr * inv_n;
    float rc = r + CULL_MARGIN;

    const float* col = colors + (size_t)p * 4;
    float* o = pd + (size_t)p * PD_STRIDE;
    o[0] = cx;
    o[1] = cy;
    o[2] = -K2EXP * r;   // c2
    o[3] = col[3];       // alpha
    o[4] = col[0];
    o[5] = col[1];
    o[6] = col[2];
    o[7] = rc * rc;      // squared cull radius
}

// One block = one 8x8 pixel tile. 8 waves; wave w composites paths
// [w*128, w*128+128) for all 64 pixels (lane = pixel), producing an affine
// map (T, A). Ordered combine across waves happens in LDS at the end.
// Path table staged in LDS: inner loop reads are ds_read_b128 with
// loop-uniform address (broadcast, conflict-free, immediate offsets).
__global__ __launch_bounds__(512) void render_kernel(
    const float* __restrict__ pd,   // (P, 8)
    float* __restrict__ out)        // (3, H, W)
{
    __shared__ float4 lds[NPATHS * 2];   // 32 KB

    // Stage path table: 2048 float4 / 512 threads = 4 each, coalesced
    const float4* src = reinterpret_cast<const float4*>(pd);
    for (int i = threadIdx.x; i < NPATHS * 2; i += 512)
        lds[i] = src[i];
    __syncthreads();

    const int wave = threadIdx.x >> 6;
    const int lane = threadIdx.x & 63;
    const int lx = lane & 7;
    const int ly = lane >> 3;
    const int xx = blockIdx.x * 8 + lx;    // 28 tiles * 8 = 224
    const int yy = blockIdx.y * 8 + ly;
    const float px = (float)xx * (1.0f / 223.0f);
    const float py = (float)yy * (1.0f / 223.0f);

    float T = 1.0f, Ar = 0.0f, Ag = 0.0f, Ab = 0.0f;
    const int base = wave * (PPW * 2);

#pragma unroll 8
    for (int p = 0; p < PPW; ++p) {
        float4 d0 = lds[base + 2 * p];       // cx, cy, c2, alpha
        float4 d1 = lds[base + 2 * p + 1];   // cr, cg, cb, rr_cull
        float dx = px - d0.x;
        float dy = py - d0.y;
        float d2 = __builtin_fmaf(dx, dx, dy * dy);
        if (__any(d2 < d1.w)) {
            float dist = __builtin_amdgcn_sqrtf(d2);
            float e = __builtin_amdgcn_exp2f(__builtin_fmaf(dist, K2EXP, d0.z));
            float m = d0.w * __builtin_amdgcn_rcpf(1.0f + e);
            float om = 1.0f - m;
            T  = T * om;
            Ar = __builtin_fmaf(Ar, om, d1.x * m);
            Ag = __builtin_fmaf(Ag, om, d1.y * m);
            Ab = __builtin_fmaf(Ab, om, d1.z * m);
        }
    }

    // Ordered combine across the 8 waves (reuse staging LDS after barrier)
    __syncthreads();
    lds[wave * 64 + lane] = make_float4(T, Ar, Ag, Ab);
    __syncthreads();

    if (wave == 0) {
        float R = 1.0f, G = 1.0f, B = 1.0f;
#pragma unroll
        for (int w = 0; w < NWAVES; ++w) {
            float4 c = lds[w * 64 + lane];
            R = __builtin_fmaf(R, c.x, c.y);
            G = __builtin_fmaf(G, c.x, c.z);
            B = __builtin_fmaf(B, c.x, c.w);
        }
        const int pix = yy * CANVAS_W + xx;
        out[pix]            = R;
        out[NPIX + pix]     = G;
        out[2 * NPIX + pix] = B;
    }
}

extern "C" void kernel_launch(void* const* d_in, const int* in_sizes, int n_in,
                              void* d_out, int out_size, void* d_ws, size_t ws_size,
                              hipStream_t stream) {
    const float* cps    = (const float*)d_in[0];
    const float* colors = (const float*)d_in[1];
    float* out = (float*)d_out;
    float* pd  = (float*)d_ws;   // 32 KB

    path_setup_kernel<<<(NPATHS + 255) / 256, 256, 0, stream>>>(cps, colors, pd);

    dim3 grid(CANVAS_W / 8, CANVAS_H / 8);   // 28 x 28 = 784 blocks
    render_kernel<<<grid, 512, 0, stream>>>(pd, out);
}

// Round 5
// 45.704 us; speedup vs baseline: 3.9421x; 1.2732x over previous
//
#include <hip/hip_runtime.h>
#include <math.h>

#define NPATHS   1024
#define CANVAS_H 224
#define CANVAS_W 224
#define NPIX     (CANVAS_H * CANVAS_W)   // 50176
#define NSAMP    49          // linspace(0,1,50)[:-1] -> t_i = i/49
#define K2EXP    72.134752f  // 50/ln(2): sigmoid(50*(r-d)) = 1/(1+exp2((d-r)*K2EXP))
#define CULL_MARGIN 0.3f     // sigmoid(-15) ~ 3e-7; worst-case total err <= 3e-4

#define NWAVES   8
#define PPW      (NPATHS / NWAVES)       // 128 paths per wave

// Per-path record (2x float4): [cx, cy, c2=-K2EXP*r, alpha | cr*a, cg*a, cb*a, rr_cull]

// One thread per (path, segment): 4096 threads. Segment partial sums reduced
// across the 4 consecutive lanes of each path via __shfl_xor.
__global__ __launch_bounds__(256) void path_setup_kernel(
    const float* __restrict__ cps,     // (P, 4, 4, 2)
    const float* __restrict__ colors,  // (P, 4)
    float* __restrict__ pd)            // (P, 8)
{
    const int tid = blockIdx.x * 256 + threadIdx.x;
    const int p = tid >> 2;
    const int s = tid & 3;

    // Segment s of path p = 8 contiguous floats = 2 float4 (32B/thread, coalesced)
    const float4* cp4 = reinterpret_cast<const float4*>(cps);
    float4 a = cp4[p * 8 + s * 2];       // x0,y0,x1,y1
    float4 b = cp4[p * 8 + s * 2 + 1];   // x2,y2,x3,y3

    // Pass 1: sum of sampled points for this segment
    float sx = 0.0f, sy = 0.0f;
    for (int i = 0; i < NSAMP; ++i) {
        float t  = (float)i * (1.0f / 49.0f);
        float mt = 1.0f - t;
        float b0 = mt * mt * mt;
        float b1 = 3.0f * mt * mt * t;
        float b2 = 3.0f * mt * t * t;
        float b3 = t * t * t;
        sx += b0 * a.x + b1 * a.z + b2 * b.x + b3 * b.z;
        sy += b0 * a.y + b1 * a.w + b2 * b.y + b3 * b.w;
    }
    // Reduce across the 4 segment lanes (lanes 4k..4k+3 share a path)
    sx += __shfl_xor(sx, 1); sx += __shfl_xor(sx, 2);
    sy += __shfl_xor(sy, 1); sy += __shfl_xor(sy, 2);
    const float inv_n = 1.0f / 196.0f;
    float cx = sx * inv_n;
    float cy = sy * inv_n;

    // Pass 2: sum of distances to center
    float sr = 0.0f;
    for (int i = 0; i < NSAMP; ++i) {
        float t  = (float)i * (1.0f / 49.0f);
        float mt = 1.0f - t;
        float b0 = mt * mt * mt;
        float b1 = 3.0f * mt * mt * t;
        float b2 = 3.0f * mt * t * t;
        float b3 = t * t * t;
        float ptx = b0 * a.x + b1 * a.z + b2 * b.x + b3 * b.z;
        float pty = b0 * a.y + b1 * a.w + b2 * b.y + b3 * b.w;
        float dx = ptx - cx;
        float dy = pty - cy;
        sr += sqrtf(dx * dx + dy * dy);
    }
    sr += __shfl_xor(sr, 1); sr += __shfl_xor(sr, 2);
    float r = sr * inv_n;

    if (s == 0) {
        float4 col = reinterpret_cast<const float4*>(colors)[p];
        float rc = r + CULL_MARGIN;
        float4* o = reinterpret_cast<float4*>(pd) + (size_t)p * 2;
        o[0] = make_float4(cx, cy, -K2EXP * r, col.w);
        o[1] = make_float4(col.x * col.w, col.y * col.w, col.z * col.w, rc * rc);
    }
}

// One block = one 8x8 pixel tile; 8 waves, wave w handles paths [128w,128w+128)
// for all 64 pixels (lane = pixel). Path records are read with a scalar
// (readfirstlane-forced) index -> s_load into SGPRs; zero vector-memory and
// zero LDS traffic in the inner loop. Ordered cross-wave combine in LDS.
__global__ __launch_bounds__(512) void render_kernel(
    const float* __restrict__ pd,   // (P, 8)
    float* __restrict__ out)        // (3, H, W)
{
    __shared__ float4 xch[NWAVES * 64];   // 8 KB

    const int wave = threadIdx.x >> 6;
    const int lane = threadIdx.x & 63;
    const int lx = lane & 7;
    const int ly = lane >> 3;
    const int xx = blockIdx.x * 8 + lx;    // 28 * 8 = 224
    const int yy = blockIdx.y * 8 + ly;
    const float px = (float)xx * (1.0f / 223.0f);
    const float py = (float)yy * (1.0f / 223.0f);

    const float4* __restrict__ pdv = reinterpret_cast<const float4*>(pd);
    const int base = __builtin_amdgcn_readfirstlane(wave * (PPW * 2));

    float T = 1.0f, Ar = 0.0f, Ag = 0.0f, Ab = 0.0f;

#pragma unroll 4
    for (int p = 0; p < PPW; ++p) {
        float4 d0 = pdv[base + 2 * p];       // cx, cy, c2, alpha
        float4 d1 = pdv[base + 2 * p + 1];   // cr*a, cg*a, cb*a, rr_cull
        float dx = px - d0.x;
        float dy = py - d0.y;
        float d2 = __builtin_fmaf(dx, dx, dy * dy);
        if (__any(d2 < d1.w)) {
            float dist = __builtin_amdgcn_sqrtf(d2);
            float e = __builtin_amdgcn_exp2f(__builtin_fmaf(dist, K2EXP, d0.z));
            float q = __builtin_amdgcn_rcpf(1.0f + e);          // sigmoid
            float om = __builtin_fmaf(-d0.w, q, 1.0f);          // 1 - alpha*q
            T  = T * om;
            Ar = __builtin_fmaf(Ar, om, d1.x * q);
            Ag = __builtin_fmaf(Ag, om, d1.y * q);
            Ab = __builtin_fmaf(Ab, om, d1.z * q);
        }
    }

    xch[wave * 64 + lane] = make_float4(T, Ar, Ag, Ab);
    __syncthreads();

    if (wave == 0) {
        float R = 1.0f, G = 1.0f, B = 1.0f;
#pragma unroll
        for (int w = 0; w < NWAVES; ++w) {
            float4 c = xch[w * 64 + lane];
            R = __builtin_fmaf(R, c.x, c.y);
            G = __builtin_fmaf(G, c.x, c.z);
            B = __builtin_fmaf(B, c.x, c.w);
        }
        const int pix = yy * CANVAS_W + xx;
        out[pix]            = R;
        out[NPIX + pix]     = G;
        out[2 * NPIX + pix] = B;
    }
}

extern "C" void kernel_launch(void* const* d_in, const int* in_sizes, int n_in,
                              void* d_out, int out_size, void* d_ws, size_t ws_size,
                              hipStream_t stream) {
    const float* cps    = (const float*)d_in[0];
    const float* colors = (const float*)d_in[1];
    float* out = (float*)d_out;
    float* pd  = (float*)d_ws;   // 32 KB

    path_setup_kernel<<<(NPATHS * 4) / 256, 256, 0, stream>>>(cps, colors, pd);

    dim3 grid(CANVAS_W / 8, CANVAS_H / 8);   // 28 x 28 = 784 blocks
    render_kernel<<<grid, 512, 0, stream>>>(pd, out);
}

// Round 6
// 45.332 us; speedup vs baseline: 3.9744x; 1.0082x over previous
//
#include <hip/hip_runtime.h>
#include <math.h>

#define NPATHS   1024
#define CANVAS_H 224
#define CANVAS_W 224
#define NPIX     (CANVAS_H * CANVAS_W)   // 50176
#define NSAMP    49          // linspace(0,1,50)[:-1] -> t_i = i/49
#define K2EXP    72.134752f  // 50/ln(2): sigmoid(50*(r-d)) = 1/(1+exp2((d-r)*K2EXP))
#define CULL_MARGIN 0.3f     // sigmoid(-15) ~ 3e-7; worst-case total err <= 3e-4

#define NWAVES   8
#define PPW      (NPATHS / NWAVES)       // 128 paths per wave

// Per-path record (2x float4): [cx, cy, c2=-K2EXP*r, alpha | cr*a, cg*a, cb*a, rr_cull]

typedef __attribute__((ext_vector_type(16))) int i16x16;

__device__ __forceinline__ float sf(int v) { return __int_as_float(v); }

// One thread per (path, segment): 4096 threads; 4-lane shfl_xor reduce.
__global__ __launch_bounds__(256) void path_setup_kernel(
    const float* __restrict__ cps,     // (P, 4, 4, 2)
    const float* __restrict__ colors,  // (P, 4)
    float* __restrict__ pd)            // (P, 8)
{
    const int tid = blockIdx.x * 256 + threadIdx.x;
    const int p = tid >> 2;
    const int s = tid & 3;

    const float4* cp4 = reinterpret_cast<const float4*>(cps);
    float4 a = cp4[p * 8 + s * 2];       // x0,y0,x1,y1
    float4 b = cp4[p * 8 + s * 2 + 1];   // x2,y2,x3,y3

    float sx = 0.0f, sy = 0.0f;
    for (int i = 0; i < NSAMP; ++i) {
        float t  = (float)i * (1.0f / 49.0f);
        float mt = 1.0f - t;
        float b0 = mt * mt * mt;
        float b1 = 3.0f * mt * mt * t;
        float b2 = 3.0f * mt * t * t;
        float b3 = t * t * t;
        sx += b0 * a.x + b1 * a.z + b2 * b.x + b3 * b.z;
        sy += b0 * a.y + b1 * a.w + b2 * b.y + b3 * b.w;
    }
    sx += __shfl_xor(sx, 1); sx += __shfl_xor(sx, 2);
    sy += __shfl_xor(sy, 1); sy += __shfl_xor(sy, 2);
    const float inv_n = 1.0f / 196.0f;
    float cx = sx * inv_n;
    float cy = sy * inv_n;

    float sr = 0.0f;
    for (int i = 0; i < NSAMP; ++i) {
        float t  = (float)i * (1.0f / 49.0f);
        float mt = 1.0f - t;
        float b0 = mt * mt * mt;
        float b1 = 3.0f * mt * mt * t;
        float b2 = 3.0f * mt * t * t;
        float b3 = t * t * t;
        float ptx = b0 * a.x + b1 * a.z + b2 * b.x + b3 * b.z;
        float pty = b0 * a.y + b1 * a.w + b2 * b.y + b3 * b.w;
        float dx = ptx - cx;
        float dy = pty - cy;
        sr += sqrtf(dx * dx + dy * dy);
    }
    sr += __shfl_xor(sr, 1); sr += __shfl_xor(sr, 2);
    float r = sr * inv_n;

    if (s == 0) {
        float4 col = reinterpret_cast<const float4*>(colors)[p];
        float rc = r + CULL_MARGIN;
        float4* o = reinterpret_cast<float4*>(pd) + (size_t)p * 2;
        o[0] = make_float4(cx, cy, -K2EXP * r, col.w);
        o[1] = make_float4(col.x * col.w, col.y * col.w, col.z * col.w, rc * rc);
    }
}

// One block = one 8x8 pixel tile; 8 waves, wave w handles paths [128w,128w+128)
// for all 64 pixels (lane = pixel). Path records are loaded via inline-asm
// s_load_dwordx16 (64B = 2 records) into SGPRs: zero vector-memory and zero
// LDS in the inner loop; VALU consumes scalar operands directly. Ordered
// cross-wave combine in LDS at the end.
__global__ __launch_bounds__(512) void render_kernel(
    const float* __restrict__ pd,   // (P, 8)
    float* __restrict__ out)        // (3, H, W)
{
    __shared__ float4 xch[NWAVES * 64];   // 8 KB

    const int wave = __builtin_amdgcn_readfirstlane((int)(threadIdx.x >> 6));
    const int lane = threadIdx.x & 63;
    const int lx = lane & 7;
    const int ly = lane >> 3;
    const int xx = blockIdx.x * 8 + lx;    // 28 * 8 = 224
    const int yy = blockIdx.y * 8 + ly;
    const float px = (float)xx * (1.0f / 223.0f);
    const float py = (float)yy * (1.0f / 223.0f);

    const float* wptr = pd + (size_t)wave * (PPW * 8);   // wave-uniform

    float T = 1.0f, Ar = 0.0f, Ag = 0.0f, Ab = 0.0f;

    for (int p = 0; p < PPW / 2; ++p) {
        i16x16 blk;
        // 64B scalar load (2 path records) + wait, fused so the data
        // dependence on blk is explicit to the compiler.
        asm volatile("s_load_dwordx16 %0, %1, 0x0\n\ts_waitcnt lgkmcnt(0)"
                     : "=s"(blk)
                     : "s"(wptr + p * 16));
#pragma unroll
        for (int j = 0; j < 2; ++j) {
            const int o = j * 8;
            float cx  = sf(blk[o + 0]);
            float cy  = sf(blk[o + 1]);
            float c2  = sf(blk[o + 2]);
            float al  = sf(blk[o + 3]);
            float cra = sf(blk[o + 4]);
            float cga = sf(blk[o + 5]);
            float cba = sf(blk[o + 6]);
            float rr  = sf(blk[o + 7]);

            float dx = px - cx;
            float dy = py - cy;
            float d2 = __builtin_fmaf(dx, dx, dy * dy);
            if (__any(d2 < rr)) {
                float dist = __builtin_amdgcn_sqrtf(d2);
                float e = __builtin_amdgcn_exp2f(__builtin_fmaf(dist, K2EXP, c2));
                float q = __builtin_amdgcn_rcpf(1.0f + e);   // sigmoid
                float om = __builtin_fmaf(-al, q, 1.0f);     // 1 - alpha*q
                T  = T * om;
                Ar = __builtin_fmaf(Ar, om, cra * q);
                Ag = __builtin_fmaf(Ag, om, cga * q);
                Ab = __builtin_fmaf(Ab, om, cba * q);
            }
        }
    }

    xch[wave * 64 + lane] = make_float4(T, Ar, Ag, Ab);
    __syncthreads();

    if (wave == 0) {
        float R = 1.0f, G = 1.0f, B = 1.0f;
#pragma unroll
        for (int w = 0; w < NWAVES; ++w) {
            float4 c = xch[w * 64 + lane];
            R = __builtin_fmaf(R, c.x, c.y);
            G = __builtin_fmaf(G, c.x, c.z);
            B = __builtin_fmaf(B, c.x, c.w);
        }
        const int pix = yy * CANVAS_W + xx;
        out[pix]            = R;
        out[NPIX + pix]     = G;
        out[2 * NPIX + pix] = B;
    }
}

extern "C" void kernel_launch(void* const* d_in, const int* in_sizes, int n_in,
                              void* d_out, int out_size, void* d_ws, size_t ws_size,
                              hipStream_t stream) {
    const float* cps    = (const float*)d_in[0];
    const float* colors = (const float*)d_in[1];
    float* out = (float*)d_out;
    float* pd  = (float*)d_ws;   // 32 KB

    path_setup_kernel<<<(NPATHS * 4) / 256, 256, 0, stream>>>(cps, colors, pd);

    dim3 grid(CANVAS_W / 8, CANVAS_H / 8);   // 28 x 28 = 784 blocks
    render_kernel<<<grid, 512, 0, stream>>>(pd, out);
}

// Round 7
// 42.565 us; speedup vs baseline: 4.2328x; 1.0650x over previous
//
#include <hip/hip_runtime.h>
#include <math.h>

#define NPATHS   1024
#define CANVAS_H 224
#define CANVAS_W 224
#define NPIX     (CANVAS_H * CANVAS_W)   // 50176
#define NSAMP    49          // linspace(0,1,50)[:-1] -> t_i = i/49
#define K2EXP    72.134752f  // 50/ln(2): sigmoid(50*(r-d)) = 1/(1+exp2((d-r)*K2EXP))
#define CULL_MARGIN 0.22f    // sigmoid(-11) ~ 1.7e-5; realistic drift ~3e-3 << 2e-2

#define NWAVES   8
#define PPW      (NPATHS / NWAVES)       // 128 paths per wave

// Per-path record (2x float4): [cx, cy, c2=-K2EXP*r, alpha | cr*a, cg*a, cb*a, rr_cull]

typedef __attribute__((ext_vector_type(16))) int   i16x16;
typedef __attribute__((ext_vector_type(2)))  float f32x2;

__device__ __forceinline__ float sf(int v) { return __int_as_float(v); }

// One thread per (path, segment): 4096 threads; 4-lane shfl_xor reduce.
__global__ __launch_bounds__(256) void path_setup_kernel(
    const float* __restrict__ cps,     // (P, 4, 4, 2)
    const float* __restrict__ colors,  // (P, 4)
    float* __restrict__ pd)            // (P, 8)
{
    const int tid = blockIdx.x * 256 + threadIdx.x;
    const int p = tid >> 2;
    const int s = tid & 3;

    const float4* cp4 = reinterpret_cast<const float4*>(cps);
    float4 a = cp4[p * 8 + s * 2];       // x0,y0,x1,y1
    float4 b = cp4[p * 8 + s * 2 + 1];   // x2,y2,x3,y3

    float sx = 0.0f, sy = 0.0f;
    for (int i = 0; i < NSAMP; ++i) {
        float t  = (float)i * (1.0f / 49.0f);
        float mt = 1.0f - t;
        float b0 = mt * mt * mt;
        float b1 = 3.0f * mt * mt * t;
        float b2 = 3.0f * mt * t * t;
        float b3 = t * t * t;
        sx += b0 * a.x + b1 * a.z + b2 * b.x + b3 * b.z;
        sy += b0 * a.y + b1 * a.w + b2 * b.y + b3 * b.w;
    }
    sx += __shfl_xor(sx, 1); sx += __shfl_xor(sx, 2);
    sy += __shfl_xor(sy, 1); sy += __shfl_xor(sy, 2);
    const float inv_n = 1.0f / 196.0f;
    float cx = sx * inv_n;
    float cy = sy * inv_n;

    float sr = 0.0f;
    for (int i = 0; i < NSAMP; ++i) {
        float t  = (float)i * (1.0f / 49.0f);
        float mt = 1.0f - t;
        float b0 = mt * mt * mt;
        float b1 = 3.0f * mt * mt * t;
        float b2 = 3.0f * mt * t * t;
        float b3 = t * t * t;
        float ptx = b0 * a.x + b1 * a.z + b2 * b.x + b3 * b.z;
        float pty = b0 * a.y + b1 * a.w + b2 * b.y + b3 * b.w;
        float dx = ptx - cx;
        float dy = pty - cy;
        sr += sqrtf(dx * dx + dy * dy);
    }
    sr += __shfl_xor(sr, 1); sr += __shfl_xor(sr, 2);
    float r = sr * inv_n;

    if (s == 0) {
        float4 col = reinterpret_cast<const float4*>(colors)[p];
        float rc = r + CULL_MARGIN;
        float4* o = reinterpret_cast<float4*>(pd) + (size_t)p * 2;
        o[0] = make_float4(cx, cy, -K2EXP * r, col.w);
        o[1] = make_float4(col.x * col.w, col.y * col.w, col.z * col.w, rc * rc);
    }
}

// One block = one 8x8 pixel tile; 8 waves, wave w handles paths [128w,128w+128)
// for all 64 pixels (lane = pixel). Path records arrive via s_load_dwordx16
// into SGPRs (zero VMEM/LDS in the loop). Inner math uses packed-fp32 pairs
// (v_pk_*). Whole-wave cull at r+0.22 skips the 3-transcendental body for
// ~30% of path-tile pairs. Ordered cross-wave combine in LDS at the end.
__global__ __launch_bounds__(512) void render_kernel(
    const float* __restrict__ pd,   // (P, 8)
    float* __restrict__ out)        // (3, H, W)
{
    __shared__ float4 xch[NWAVES * 64];   // 8 KB

    const int wave = __builtin_amdgcn_readfirstlane((int)(threadIdx.x >> 6));
    const int lane = threadIdx.x & 63;
    const int lx = lane & 7;
    const int ly = lane >> 3;
    const int xx = blockIdx.x * 8 + lx;    // 28 * 8 = 224
    const int yy = blockIdx.y * 8 + ly;

    f32x2 pxy;
    pxy.x = (float)xx * (1.0f / 223.0f);
    pxy.y = (float)yy * (1.0f / 223.0f);

    const float* wptr = pd + (size_t)wave * (PPW * 8);   // wave-uniform

    float T = 1.0f, Ab = 0.0f;
    f32x2 ra; ra.x = 0.0f; ra.y = 0.0f;   // (Ar, Ag)

    for (int p = 0; p < PPW / 2; ++p) {
        i16x16 blk;
        asm volatile("s_load_dwordx16 %0, %1, 0x0\n\ts_waitcnt lgkmcnt(0)"
                     : "=s"(blk)
                     : "s"(wptr + p * 16));
#pragma unroll
        for (int j = 0; j < 2; ++j) {
            const int o = j * 8;
            f32x2 cxy;
            cxy.x = sf(blk[o + 0]);
            cxy.y = sf(blk[o + 1]);
            float c2  = sf(blk[o + 2]);
            float al  = sf(blk[o + 3]);
            float rr  = sf(blk[o + 7]);

            f32x2 dxy = pxy - cxy;           // v_pk_add
            f32x2 sq  = dxy * dxy;           // v_pk_mul
            float d2  = sq.x + sq.y;
            if (__any(d2 < rr)) {
                float dist = __builtin_amdgcn_sqrtf(d2);
                float e = __builtin_amdgcn_exp2f(__builtin_fmaf(dist, K2EXP, c2));
                float q = __builtin_amdgcn_rcpf(1.0f + e);   // sigmoid
                float om = __builtin_fmaf(-al, q, 1.0f);     // 1 - alpha*q

                f32x2 crg;                    // (cr*a, cg*a)
                crg.x = sf(blk[o + 4]);
                crg.y = sf(blk[o + 5]);
                float cba = sf(blk[o + 6]);

                f32x2 om2; om2.x = om; om2.y = om;
                ra = ra * om2 + crg * (f32x2){q, q};         // pk_mul + pk_fma
                T  = T * om;
                Ab = __builtin_fmaf(Ab, om, cba * q);
            }
        }
    }

    xch[wave * 64 + lane] = make_float4(T, ra.x, ra.y, Ab);
    __syncthreads();

    if (wave == 0) {
        float R = 1.0f, G = 1.0f, B = 1.0f;
#pragma unroll
        for (int w = 0; w < NWAVES; ++w) {
            float4 c = xch[w * 64 + lane];
            R = __builtin_fmaf(R, c.x, c.y);
            G = __builtin_fmaf(G, c.x, c.z);
            B = __builtin_fmaf(B, c.x, c.w);
        }
        const int pix = yy * CANVAS_W + xx;
        out[pix]            = R;
        out[NPIX + pix]     = G;
        out[2 * NPIX + pix] = B;
    }
}

extern "C" void kernel_launch(void* const* d_in, const int* in_sizes, int n_in,
                              void* d_out, int out_size, void* d_ws, size_t ws_size,
                              hipStream_t stream) {
    const float* cps    = (const float*)d_in[0];
    const float* colors = (const float*)d_in[1];
    float* out = (float*)d_out;
    float* pd  = (float*)d_ws;   // 32 KB

    path_setup_kernel<<<(NPATHS * 4) / 256, 256, 0, stream>>>(cps, colors, pd);

    dim3 grid(CANVAS_W / 8, CANVAS_H / 8);   // 28 x 28 = 784 blocks
    render_kernel<<<grid, 512, 0, stream>>>(pd, out);
}